// Round 10
// baseline (279.791 us; speedup 1.0000x reference)
//
#include <hip/hip_runtime.h>

#define N_ 100000
#define E_ 1600000
#define HD 128
#define NB 391      // dst buckets of 256 nodes (391*256 = 100096 >= N_)
#define GB 256      // binning blocks
#define CHK 6250    // edges per binning block (256*6250 = 1.6M exact)
#define NBGB (NB * GB)

typedef unsigned short u16;
typedef unsigned int u32;
typedef __bf16 bf16x8 __attribute__((ext_vector_type(8)));
typedef float f32x4 __attribute__((ext_vector_type(4)));

// packed-weight offsets (u16 elements)
#define OFF_W2 0
#define OFF_W3 16384
#define OFF_WL 32768
#define OFF_P2 49152
#define OFF_P1 65536
#define PK_TOT 98304   // hi plane size; lo plane at +PK_TOT

__device__ __forceinline__ u16 f2bf(float f) {
    u32 u = __float_as_uint(f);
    return (u16)((u + 0x7FFFu + ((u >> 16) & 1u)) >> 16);
}
__device__ __forceinline__ float bf2f(u16 h) {
    return __uint_as_float(((u32)h) << 16);
}
__device__ __forceinline__ f32x4 mfma16(uint4 a, uint4 b, f32x4 c) {
    return __builtin_amdgcn_mfma_f32_16x16x32_bf16(
        __builtin_bit_cast(bf16x8, a), __builtin_bit_cast(bf16x8, b), c, 0, 0, 0);
}

// Activation LDS layout (u16, [rows][128]): idx = row*128 + (col ^ ((row&7)<<3))
__device__ __forceinline__ uint4 ldsA(const u16* A, int row, int kt, int l) {
    int idx = row * 128 + (((kt * 32 + ((l >> 4) << 3))) ^ ((row & 7) << 3));
    return *(const uint4*)&A[idx];
}

// write C fragment (col=16*nt+(l&15), row=16*mt+4*(l>>4)+r) as ReLU'd bf16 (hi only)
__device__ __forceinline__ void writeActH(u16* Ah, f32x4 acc, int mt, int nt, int l) {
    const int col = nt * 16 + (l & 15);
#pragma unroll
    for (int r = 0; r < 4; ++r) {
        const int row = mt * 16 + ((l >> 4) << 2) + r;
        Ah[row * 128 + (col ^ ((row & 7) << 3))] = f2bf(fmaxf(acc[r], 0.f));
    }
}

// One MFMA layer slice: wave owns n-tile nt. Weights hi/lo 2-product, act hi only.
template<int MT, int KT>
__device__ __forceinline__ void mfmaLayerW(const u16* Ah,
                                           const u16* __restrict__ wph,
                                           const u16* __restrict__ wpl,
                                           const float* __restrict__ bias,
                                           int nt, int l, f32x4 acc[MT])
{
    const float bv = bias[nt * 16 + (l & 15)];
#pragma unroll
    for (int mt = 0; mt < MT; ++mt) {
        acc[mt][0] = bv; acc[mt][1] = bv; acc[mt][2] = bv; acc[mt][3] = bv;
    }
#pragma unroll
    for (int kt = 0; kt < KT; ++kt) {
        uint4 bh = *(const uint4*)&wph[((nt * KT + kt) * 64 + l) * 8];
        uint4 bl = *(const uint4*)&wpl[((nt * KT + kt) * 64 + l) * 8];
#pragma unroll
        for (int mt = 0; mt < MT; ++mt) {
            uint4 ah = ldsA(Ah, mt * 16 + (l & 15), kt, l);
            acc[mt] = mfma16(ah, bl, acc[mt]);
            acc[mt] = mfma16(ah, bh, acc[mt]);
        }
    }
}

// ---------------------------------------------------------------------------
// Weight pre-pack: fragment-ordered bf16 hi/lo planes.
// ---------------------------------------------------------------------------
__global__ __launch_bounds__(256) void k_pack(
    const float* __restrict__ W2, const float* __restrict__ W3,
    const float* __restrict__ Wl, const float* __restrict__ P2,
    const float* __restrict__ P1, u16* __restrict__ wpk)
{
    int e = blockIdx.x * 256 + threadIdx.x;
    if (e >= PK_TOT) return;
    const float* src; int local, KT;
    if (e < OFF_P1) {
        int m = e >> 14;
        src = (m == 0) ? W2 : (m == 1) ? W3 : (m == 2) ? Wl : P2;
        local = e & 16383; KT = 4;
    } else {
        src = P1; local = e - OFF_P1; KT = 8;
    }
    int j = local & 7, lane = (local >> 3) & 63, t = local >> 9;
    int kt = t % KT, nt = t / KT;
    int k = kt * 32 + ((lane >> 4) << 3) + j;
    int n = nt * 16 + (lane & 15);
    float v = src[k * HD + n];
    u16 h = f2bf(v);
    wpk[e] = h;
    wpk[PK_TOT + e] = f2bf(v - bf2f(h));
}

// ---------------------------------------------------------------------------
// layer1 (16 -> 128) VALU fp32 -> bf16 LDS (hi only). NPH rows per thread-group.
// ---------------------------------------------------------------------------
template<int NPH>
__device__ __forceinline__ void layer1(const float xs[][16],
                                       const float* __restrict__ W1,
                                       const float* __restrict__ b1,
                                       u16* Uh, int f, int g)
{
    float w[16];
#pragma unroll
    for (int j = 0; j < 16; ++j) w[j] = W1[j * HD + f];
    const float bb = b1[f];
#pragma unroll
    for (int nn = 0; nn < NPH; ++nn) {
        const int row = g * NPH + nn;
        const float4* h4 = (const float4*)xs[row];
        float4 h0 = h4[0], h1 = h4[1], h2 = h4[2], h3 = h4[3];
        float a = bb
            + h0.x * w[0] + h0.y * w[1] + h0.z * w[2] + h0.w * w[3]
            + h1.x * w[4] + h1.y * w[5] + h1.z * w[6] + h1.w * w[7]
            + h2.x * w[8] + h2.y * w[9] + h2.z * w[10] + h2.w * w[11]
            + h3.x * w[12] + h3.y * w[13] + h3.z * w[14] + h3.w * w[15];
        Uh[row * 128 + (f ^ ((row & 7) << 3))] = f2bf(fmaxf(a, 0.f));
    }
}

// ---------------------------------------------------------------------------
// K1: mlp_pre + lin -> msg16 (bf16) + pre16 (bf16).
// 64 nodes / 512-thread block (8 waves, one n-tile each, MT=4). LDS 36 KB.
// ---------------------------------------------------------------------------
__global__ __launch_bounds__(512) void k_msg(
    const float* __restrict__ x,
    const float* __restrict__ W1, const float* __restrict__ b1,
    const float* __restrict__ b2, const float* __restrict__ b3,
    const float* __restrict__ blin,
    const u16* __restrict__ wpk, u16* __restrict__ msg16,
    u16* __restrict__ pre16)
{
    __shared__ float xs[64][16];
    __shared__ __align__(16) u16 Uh[8192], Vh[8192];
    const int tid = threadIdx.x;
    const int l = tid & 63, w = tid >> 6;   // w in [0,8)
    const int base = blockIdx.x * 64;

    for (int i = tid; i < 64 * 16; i += 512) {
        int node = min(base + (i >> 4), N_ - 1);   // clamp OOB reads
        xs[i >> 4][i & 15] = x[node * 16 + (i & 15)];
    }
    __syncthreads();

    layer1<16>(xs, W1, b1, Uh, tid & 127, tid >> 7);
    __syncthreads();

    f32x4 acc[4];
    // W2: U -> V
    mfmaLayerW<4, 4>(Uh, wpk + OFF_W2, wpk + PK_TOT + OFF_W2, b2, w, l, acc);
#pragma unroll
    for (int mt = 0; mt < 4; ++mt) writeActH(Vh, acc[mt], mt, w, l);
    __syncthreads();

    // W3: V -> U (U = pre)
    mfmaLayerW<4, 4>(Vh, wpk + OFF_W3, wpk + PK_TOT + OFF_W3, b3, w, l, acc);
#pragma unroll
    for (int mt = 0; mt < 4; ++mt) writeActH(Uh, acc[mt], mt, w, l);
    __syncthreads();

    // lin: U -> V (bf16 msg)
    mfmaLayerW<4, 4>(Uh, wpk + OFF_WL, wpk + PK_TOT + OFF_WL, blin, w, l, acc);
#pragma unroll
    for (int mt = 0; mt < 4; ++mt) writeActH(Vh, acc[mt], mt, w, l);
    __syncthreads();

    // coalesced stores: msg = Vh, pre = Uh (guard OOB rows)
#pragma unroll
    for (int chunk = 0; chunk < 2; ++chunk) {
        int e = tid * 8 + chunk * 4096;
        int r = e >> 7, c0 = e & 127;
        if (base + r < N_) {
            int idx = r * HD + (c0 ^ ((r & 7) << 3));
            size_t g = (size_t)(base + r) * HD + c0;
            *(uint4*)&msg16[g] = *(const uint4*)&Vh[idx];
            *(uint4*)&pre16[g] = *(const uint4*)&Uh[idx];
        }
    }
}

// ---------------------------------------------------------------------------
// CSR build, bucketed (dst>>8): count -> scan -> scatter -> fill.
// ---------------------------------------------------------------------------
__global__ __launch_bounds__(256) void k_count(const int* __restrict__ dst,
                                               int* __restrict__ cnt)
{
    __shared__ int lc[NB];
    const int tid = threadIdx.x;
    for (int i = tid; i < NB; i += 256) lc[i] = 0;
    __syncthreads();
    const int e0 = blockIdx.x * CHK, e1 = min(e0 + CHK, E_);
    for (int e = e0 + tid; e < e1; e += 256)
        atomicAdd(&lc[dst[e] >> 8], 1);
    __syncthreads();
    for (int i = tid; i < NB; i += 256) cnt[i * GB + blockIdx.x] = lc[i];
}

__global__ void k_bsum(const int* __restrict__ v, int* __restrict__ part, int L)
{
    __shared__ int s[256];
    int i = blockIdx.x * 256 + threadIdx.x;
    int t = threadIdx.x;
    s[t] = (i < L) ? v[i] : 0;
    __syncthreads();
    for (int st = 128; st > 0; st >>= 1) {
        if (t < st) s[t] += s[t + st];
        __syncthreads();
    }
    if (t == 0) part[blockIdx.x] = s[0];
}

__global__ void k_pscan(const int* __restrict__ part, int* __restrict__ poff, int nb)
{
    __shared__ int s[512];
    int t = threadIdx.x;
    int d = (t < nb) ? part[t] : 0;
    s[t] = d;
    __syncthreads();
    for (int st = 1; st < 512; st <<= 1) {
        int v = (t >= st) ? s[t - st] : 0;
        __syncthreads();
        s[t] += v;
        __syncthreads();
    }
    if (t < nb) poff[t] = s[t] - d;
}

__global__ void k_scan_excl(const int* __restrict__ v, const int* __restrict__ poff,
                            int* __restrict__ outp, int L)
{
    __shared__ int s[256];
    int i = blockIdx.x * 256 + threadIdx.x;
    int t = threadIdx.x;
    int d = (i < L) ? v[i] : 0;
    s[t] = d;
    __syncthreads();
    for (int st = 1; st < 256; st <<= 1) {
        int vv = (t >= st) ? s[t - st] : 0;
        __syncthreads();
        s[t] += vv;
        __syncthreads();
    }
    if (i < L) outp[i] = s[t] - d + poff[blockIdx.x];
}

// Phase C: scatter edges into bucket-ordered ebuf (uint2{src,dst}).
__global__ __launch_bounds__(256) void k_scatter(const int* __restrict__ src,
                                                 const int* __restrict__ dst,
                                                 const int* __restrict__ escan,
                                                 uint2* __restrict__ ebuf)
{
    __shared__ int lcur[NB];
    const int tid = threadIdx.x;
    for (int i = tid; i < NB; i += 256) lcur[i] = escan[i * GB + blockIdx.x];
    __syncthreads();
    const int e0 = blockIdx.x * CHK, e1 = min(e0 + CHK, E_);
    for (int e = e0 + tid; e < e1; e += 256) {
        int s = src[e], d = dst[e];
        int pos = atomicAdd(&lcur[d >> 8], 1);
        ebuf[pos] = uint2{(u32)s, (u32)d};
    }
}

// Phase D: per-bucket node offsets (LDS hist+scan) + csr fill. One block/bucket.
__global__ __launch_bounds__(256) void k_fill2(const uint2* __restrict__ ebuf,
                                               const int* __restrict__ escan,
                                               int* __restrict__ offs,
                                               int* __restrict__ endp,
                                               int* __restrict__ csr)
{
    __shared__ int hist[256], sc[256], cur[256];
    const int tid = threadIdx.x, b = blockIdx.x;
    const int s = escan[b * GB];
    const int e = (b == NB - 1) ? E_ : escan[(b + 1) * GB];
    hist[tid] = 0;
    __syncthreads();
    for (int i = s + tid; i < e; i += 256)
        atomicAdd(&hist[ebuf[i].y & 255], 1);
    __syncthreads();
    int d = hist[tid];
    sc[tid] = d;
    __syncthreads();
    for (int st = 1; st < 256; st <<= 1) {
        int v = (tid >= st) ? sc[tid - st] : 0;
        __syncthreads();
        sc[tid] += v;
        __syncthreads();
    }
    int ex = s + sc[tid] - d;
    int node = (b << 8) + tid;
    if (node < N_) { offs[node] = ex; endp[node] = ex + d; }
    cur[tid] = ex;
    __syncthreads();
    for (int i = s + tid; i < e; i += 256) {
        uint2 u = ebuf[i];
        int pos = atomicAdd(&cur[u.y & 255], 1);
        csr[pos] = u.x;
    }
}

// ---------------------------------------------------------------------------
// K2b: gather. One wave/node; lane covers 8 B (4 bf16 cols) via dwordx2;
// lane-halves process even/odd edges (2 edges per load inst), combine with
// shfl_xor(32). Unroll: 8 edges in flight.
// ---------------------------------------------------------------------------
__global__ __launch_bounds__(256) void k_agg(
    const u16* __restrict__ msg16, const int* __restrict__ csr,
    const int* __restrict__ offs, const int* __restrict__ endp,
    u32* __restrict__ agg16)
{
    const int w = threadIdx.x >> 6, l = threadIdx.x & 63;
    const int node = blockIdx.x * 4 + w;
    if (node >= N_) return;
    const int c = l & 31, h = l >> 5;
    const int s = offs[node], e = endp[node];
    float a0 = 0.f, a1 = 0.f, a2 = 0.f, a3 = 0.f;
    int i = s;
    for (; i + 8 <= e; i += 8) {
        uint2 d[4];
#pragma unroll
        for (int q = 0; q < 4; ++q) {
            int src = csr[i + 2 * q + h];
            d[q] = *(const uint2*)&((const u32*)(msg16 + (size_t)src * HD))[2 * c];
        }
#pragma unroll
        for (int q = 0; q < 4; ++q) {
            a0 += __uint_as_float(d[q].x << 16);
            a1 += __uint_as_float(d[q].x & 0xffff0000u);
            a2 += __uint_as_float(d[q].y << 16);
            a3 += __uint_as_float(d[q].y & 0xffff0000u);
        }
    }
    for (; i + 2 <= e; i += 2) {
        int src = csr[i + h];
        uint2 d = *(const uint2*)&((const u32*)(msg16 + (size_t)src * HD))[2 * c];
        a0 += __uint_as_float(d.x << 16);
        a1 += __uint_as_float(d.x & 0xffff0000u);
        a2 += __uint_as_float(d.y << 16);
        a3 += __uint_as_float(d.y & 0xffff0000u);
    }
    if (i < e && h == 0) {
        int src = csr[i];
        uint2 d = *(const uint2*)&((const u32*)(msg16 + (size_t)src * HD))[2 * c];
        a0 += __uint_as_float(d.x << 16);
        a1 += __uint_as_float(d.x & 0xffff0000u);
        a2 += __uint_as_float(d.y << 16);
        a3 += __uint_as_float(d.y & 0xffff0000u);
    }
    a0 += __shfl_xor(a0, 32);
    a1 += __shfl_xor(a1, 32);
    a2 += __shfl_xor(a2, 32);
    a3 += __shfl_xor(a3, 32);
    if (h == 0) {
        uint2 o;
        o.x = ((u32)f2bf(a1) << 16) | (u32)f2bf(a0);
        o.y = ((u32)f2bf(a3) << 16) | (u32)f2bf(a2);
        *(uint2*)&agg16[(size_t)node * 64 + 2 * c] = o;
    }
}

// ---------------------------------------------------------------------------
// K3: pre16 + agg16 -> P1 -> P2 -> P3 -> out.
// 64 nodes / 512-thread block (8 waves, one n-tile each, MT=4). LDS 32 KB.
// ---------------------------------------------------------------------------
__global__ __launch_bounds__(512) void k_post(
    const u16* __restrict__ pre16, const u32* __restrict__ agg16,
    const float* __restrict__ pb1, const float* __restrict__ pb2,
    const float* __restrict__ P3, const float* __restrict__ pb3,
    const u16* __restrict__ wpk, float* __restrict__ out)
{
    __shared__ __align__(16) u16 Uh[8192], Vh[8192];
    const int tid = threadIdx.x;
    const int l = tid & 63, w = tid >> 6;
    const int base = blockIdx.x * 64;

    // load pre -> Uh, agg -> Vh (clamp OOB rows; their outputs are discarded)
#pragma unroll
    for (int chunk = 0; chunk < 2; ++chunk) {
        int e = tid * 8 + chunk * 4096;
        int r = e >> 7, c0 = e & 127;
        int idx = r * HD + (c0 ^ ((r & 7) << 3));
        size_t g = (size_t)min(base + r, N_ - 1) * HD + c0;
        *(uint4*)&Uh[idx] = *(const uint4*)&pre16[g];
        *(uint4*)&Vh[idx] = *(const uint4*)&agg16[g >> 1];
    }
    __syncthreads();

    f32x4 acc[4];
    // P1 (K=256): kt 0-3 from Uh (pre), kt 4-7 from Vh (agg)
    {
        const float bv = pb1[w * 16 + (l & 15)];
#pragma unroll
        for (int mt = 0; mt < 4; ++mt) {
            acc[mt][0] = bv; acc[mt][1] = bv; acc[mt][2] = bv; acc[mt][3] = bv;
        }
#pragma unroll
        for (int kt = 0; kt < 8; ++kt) {
            const u16* sh = (kt < 4) ? Uh : Vh;
            uint4 bh = *(const uint4*)&wpk[OFF_P1 + ((w * 8 + kt) * 64 + l) * 8];
            uint4 bl = *(const uint4*)&wpk[PK_TOT + OFF_P1 + ((w * 8 + kt) * 64 + l) * 8];
#pragma unroll
            for (int mt = 0; mt < 4; ++mt) {
                uint4 ah = ldsA(sh, mt * 16 + (l & 15), kt & 3, l);
                acc[mt] = mfma16(ah, bl, acc[mt]);
                acc[mt] = mfma16(ah, bh, acc[mt]);
            }
        }
    }
    __syncthreads();   // all P1 reads of Uh done before overwrite
#pragma unroll
    for (int mt = 0; mt < 4; ++mt) writeActH(Uh, acc[mt], mt, w, l);
    __syncthreads();

    // P2: U -> V (bf16, ReLU'd)
    mfmaLayerW<4, 4>(Uh, wpk + OFF_P2, wpk + PK_TOT + OFF_P2, pb2, w, l, acc);
#pragma unroll
    for (int mt = 0; mt < 4; ++mt) writeActH(Vh, acc[mt], mt, w, l);
    __syncthreads();

    // P3: 128 -> 16 + outer ReLU (VALU fp32; 512 thr, 2 passes over 64 nodes)
    {
        const int o = tid & 15;
#pragma unroll
        for (int p = 0; p < 2; ++p) {
            const int n = p * 32 + (tid >> 4);
            const int sn = (n & 7) << 3;
            float a = pb3[o];
            for (int k0 = 0; k0 < HD; k0 += 8) {
                uint4 ph = *(const uint4*)&Vh[n * HD + (k0 ^ sn)];
                const u32 pw[4] = {ph.x, ph.y, ph.z, ph.w};
#pragma unroll
                for (int j = 0; j < 8; ++j) {
                    u32 hv = (j & 1) ? (pw[j >> 1] & 0xffff0000u) : (pw[j >> 1] << 16);
                    a += __uint_as_float(hv) * P3[(k0 + j) * 16 + o];
                }
            }
            if (base + n < N_)
                out[(size_t)(base + n) * 16 + o] = fmaxf(a, 0.f);
        }
    }
}

// ---------------------------------------------------------------------------
extern "C" void kernel_launch(void* const* d_in, const int* in_sizes, int n_in,
                              void* d_out, int out_size, void* d_ws, size_t ws_size,
                              hipStream_t stream)
{
    const float* x  = (const float*)d_in[0];
    const int*   ei = (const int*)d_in[1];
    const float* W1 = (const float*)d_in[2];  const float* b1  = (const float*)d_in[3];
    const float* W2 = (const float*)d_in[4];  const float* b2  = (const float*)d_in[5];
    const float* W3 = (const float*)d_in[6];  const float* b3  = (const float*)d_in[7];
    const float* Wl = (const float*)d_in[8];  const float* bl  = (const float*)d_in[9];
    const float* P1 = (const float*)d_in[10]; const float* pb1 = (const float*)d_in[11];
    const float* P2 = (const float*)d_in[12]; const float* pb2 = (const float*)d_in[13];
    const float* P3 = (const float*)d_in[14]; const float* pb3 = (const float*)d_in[15];
    float* out = (float*)d_out;

    // Workspace ~85.8 MB total
    char* ws = (char*)d_ws;
    u16* msg16  = (u16*)ws;   ws += (size_t)N_ * HD * 2;
    u32* agg16  = (u32*)ws;   ws += (size_t)N_ * 64 * 4;
    uint2* ebuf = (uint2*)agg16;                     // alias: dead before k_agg writes
    int* csr    = (int*)ws;   ws += (size_t)E_ * 4;
    int* offs   = (int*)ws;   ws += (size_t)N_ * 4;
    int* endp   = (int*)ws;   ws += (size_t)N_ * 4;
    int* cnt    = (int*)ws;   ws += (size_t)NBGB * 4;
    int* escan  = (int*)ws;   ws += (size_t)NBGB * 4;
    int* partC  = (int*)ws;   ws += 512 * 4;
    int* poffC  = (int*)ws;   ws += 512 * 4;
    u16* wpk    = (u16*)ws;   ws += (size_t)2 * PK_TOT * 2;
    u16* pre16  = (u16*)ws;   ws += (size_t)N_ * HD * 2;

    const int* srcv = ei;
    const int* dstv = ei + E_;
    const int nbC = NBGB / 256;          // 391 (exact)
    const int nbM = (N_ + 63) / 64;      // 1563

    k_pack<<<(PK_TOT + 255) / 256, 256, 0, stream>>>(W2, W3, Wl, P2, P1, wpk);
    k_msg<<<nbM, 512, 0, stream>>>(x, W1, b1, b2, b3, bl, wpk, msg16, pre16);
    k_count<<<GB, 256, 0, stream>>>(dstv, cnt);
    k_bsum<<<nbC, 256, 0, stream>>>(cnt, partC, NBGB);
    k_pscan<<<1, 512, 0, stream>>>(partC, poffC, nbC);
    k_scan_excl<<<nbC, 256, 0, stream>>>(cnt, poffC, escan, NBGB);
    k_scatter<<<GB, 256, 0, stream>>>(srcv, dstv, escan, ebuf);
    k_fill2<<<NB, 256, 0, stream>>>(ebuf, escan, offs, endp, csr);
    k_agg<<<(N_ + 3) / 4, 256, 0, stream>>>(msg16, csr, offs, endp, agg16);
    k_post<<<nbM, 512, 0, stream>>>(pre16, agg16, pb1, pb2, P3, pb3, wpk, out);
}

// Round 11
// 206.190 us; speedup vs baseline: 1.3570x; 1.3570x over previous
//
#include <hip/hip_runtime.h>

#define N_ 100000
#define E_ 1600000
#define HD 128
#define NB 391      // dst buckets of 256 nodes (391*256 = 100096 >= N_)
#define GB 256      // binning blocks
#define CHK 6250    // edges per binning block (256*6250 = 1.6M exact)
#define NBGB (NB * GB)

typedef unsigned short u16;
typedef unsigned int u32;
typedef __bf16 bf16x8 __attribute__((ext_vector_type(8)));
typedef float f32x4 __attribute__((ext_vector_type(4)));

// packed-weight offsets (u16 elements)
#define OFF_W2 0
#define OFF_W3 16384
#define OFF_WL 32768
#define OFF_P2 49152
#define OFF_P1 65536
#define PK_TOT 98304   // hi plane size; lo plane at +PK_TOT

__device__ __forceinline__ u16 f2bf(float f) {
    u32 u = __float_as_uint(f);
    return (u16)((u + 0x7FFFu + ((u >> 16) & 1u)) >> 16);
}
__device__ __forceinline__ float bf2f(u16 h) {
    return __uint_as_float(((u32)h) << 16);
}
__device__ __forceinline__ f32x4 mfma16(uint4 a, uint4 b, f32x4 c) {
    return __builtin_amdgcn_mfma_f32_16x16x32_bf16(
        __builtin_bit_cast(bf16x8, a), __builtin_bit_cast(bf16x8, b), c, 0, 0, 0);
}

// Activation LDS layout (u16, [rows][128]): idx = row*128 + (col ^ ((row&7)<<3))
__device__ __forceinline__ uint4 ldsA(const u16* A, int row, int kt, int l) {
    int idx = row * 128 + (((kt * 32 + ((l >> 4) << 3))) ^ ((row & 7) << 3));
    return *(const uint4*)&A[idx];
}

// write C fragment (col=16*nt+(l&15), row=16*mt+4*(l>>4)+r) as ReLU'd bf16 (hi only)
__device__ __forceinline__ void writeActH(u16* Ah, f32x4 acc, int mt, int nt, int l) {
    const int col = nt * 16 + (l & 15);
#pragma unroll
    for (int r = 0; r < 4; ++r) {
        const int row = mt * 16 + ((l >> 4) << 2) + r;
        Ah[row * 128 + (col ^ ((row & 7) << 3))] = f2bf(fmaxf(acc[r], 0.f));
    }
}

// One MFMA layer slice: wave owns n-tile nt. Weights hi/lo 2-product, act hi only.
// MT=2 / 32-node blocks / VGPR~128 is the proven sweet spot: MT=4 (round 10)
// made the allocator drop to 80 VGPR and serialize ds_read->MFMA (2.5x slower).
template<int MT, int KT>
__device__ __forceinline__ void mfmaLayerW(const u16* Ah,
                                           const u16* __restrict__ wph,
                                           const u16* __restrict__ wpl,
                                           const float* __restrict__ bias,
                                           int nt, int l, f32x4 acc[MT])
{
    const float bv = bias[nt * 16 + (l & 15)];
#pragma unroll
    for (int mt = 0; mt < MT; ++mt) {
        acc[mt][0] = bv; acc[mt][1] = bv; acc[mt][2] = bv; acc[mt][3] = bv;
    }
#pragma unroll
    for (int kt = 0; kt < KT; ++kt) {
        uint4 bh = *(const uint4*)&wph[((nt * KT + kt) * 64 + l) * 8];
        uint4 bl = *(const uint4*)&wpl[((nt * KT + kt) * 64 + l) * 8];
#pragma unroll
        for (int mt = 0; mt < MT; ++mt) {
            uint4 ah = ldsA(Ah, mt * 16 + (l & 15), kt, l);
            acc[mt] = mfma16(ah, bl, acc[mt]);
            acc[mt] = mfma16(ah, bh, acc[mt]);
        }
    }
}

// ---------------------------------------------------------------------------
// Weight pre-pack: fragment-ordered bf16 hi/lo planes.
// ---------------------------------------------------------------------------
__global__ __launch_bounds__(256) void k_pack(
    const float* __restrict__ W2, const float* __restrict__ W3,
    const float* __restrict__ Wl, const float* __restrict__ P2,
    const float* __restrict__ P1, u16* __restrict__ wpk)
{
    int e = blockIdx.x * 256 + threadIdx.x;
    if (e >= PK_TOT) return;
    const float* src; int local, KT;
    if (e < OFF_P1) {
        int m = e >> 14;
        src = (m == 0) ? W2 : (m == 1) ? W3 : (m == 2) ? Wl : P2;
        local = e & 16383; KT = 4;
    } else {
        src = P1; local = e - OFF_P1; KT = 8;
    }
    int j = local & 7, lane = (local >> 3) & 63, t = local >> 9;
    int kt = t % KT, nt = t / KT;
    int k = kt * 32 + ((lane >> 4) << 3) + j;
    int n = nt * 16 + (lane & 15);
    float v = src[k * HD + n];
    u16 h = f2bf(v);
    wpk[e] = h;
    wpk[PK_TOT + e] = f2bf(v - bf2f(h));
}

// ---------------------------------------------------------------------------
// layer1 (16 -> 128) VALU fp32 -> bf16 LDS (hi only). 512 thr: g=tid>>7, NPH=8.
// ---------------------------------------------------------------------------
template<int NPH>
__device__ __forceinline__ void layer1(const float xs[][16],
                                       const float* __restrict__ W1,
                                       const float* __restrict__ b1,
                                       u16* Uh, int f, int g)
{
    float w[16];
#pragma unroll
    for (int j = 0; j < 16; ++j) w[j] = W1[j * HD + f];
    const float bb = b1[f];
#pragma unroll
    for (int nn = 0; nn < NPH; ++nn) {
        const int row = g * NPH + nn;
        const float4* h4 = (const float4*)xs[row];
        float4 h0 = h4[0], h1 = h4[1], h2 = h4[2], h3 = h4[3];
        float a = bb
            + h0.x * w[0] + h0.y * w[1] + h0.z * w[2] + h0.w * w[3]
            + h1.x * w[4] + h1.y * w[5] + h1.z * w[6] + h1.w * w[7]
            + h2.x * w[8] + h2.y * w[9] + h2.z * w[10] + h2.w * w[11]
            + h3.x * w[12] + h3.y * w[13] + h3.z * w[14] + h3.w * w[15];
        Uh[row * 128 + (f ^ ((row & 7) << 3))] = f2bf(fmaxf(a, 0.f));
    }
}

// ---------------------------------------------------------------------------
// K1: mlp_pre + lin -> msg16 (bf16) + pre16 (bf16).
// 32 nodes / 512-thread block (8 waves, one n-tile each). LDS 18 KB.
// ---------------------------------------------------------------------------
__global__ __launch_bounds__(512) void k_msg(
    const float* __restrict__ x,
    const float* __restrict__ W1, const float* __restrict__ b1,
    const float* __restrict__ b2, const float* __restrict__ b3,
    const float* __restrict__ blin,
    const u16* __restrict__ wpk, u16* __restrict__ msg16,
    u16* __restrict__ pre16)
{
    __shared__ float xs[32][16];
    __shared__ __align__(16) u16 Uh[4096], Vh[4096];
    const int tid = threadIdx.x;
    const int l = tid & 63, w = tid >> 6;   // w in [0,8)
    const int base = blockIdx.x * 32;

    xs[tid >> 4][tid & 15] = x[(base + (tid >> 4)) * 16 + (tid & 15)];
    __syncthreads();

    layer1<8>(xs, W1, b1, Uh, tid & 127, tid >> 7);
    __syncthreads();

    f32x4 acc[2];
    // W2: U -> V
    mfmaLayerW<2, 4>(Uh, wpk + OFF_W2, wpk + PK_TOT + OFF_W2, b2, w, l, acc);
    writeActH(Vh, acc[0], 0, w, l);
    writeActH(Vh, acc[1], 1, w, l);
    __syncthreads();

    // W3: V -> U (U = pre)
    mfmaLayerW<2, 4>(Vh, wpk + OFF_W3, wpk + PK_TOT + OFF_W3, b3, w, l, acc);
    writeActH(Uh, acc[0], 0, w, l);
    writeActH(Uh, acc[1], 1, w, l);
    __syncthreads();

    // lin: U -> V (bf16 msg)
    mfmaLayerW<2, 4>(Uh, wpk + OFF_WL, wpk + PK_TOT + OFF_WL, blin, w, l, acc);
    writeActH(Vh, acc[0], 0, w, l);
    writeActH(Vh, acc[1], 1, w, l);
    __syncthreads();

    // coalesced stores: msg = Vh, pre = Uh
    {
        int e = tid * 8;
        int r = e >> 7, c0 = e & 127;
        int idx = r * HD + (c0 ^ ((r & 7) << 3));
        size_t g = (size_t)(base + r) * HD + c0;
        *(uint4*)&msg16[g] = *(const uint4*)&Vh[idx];
        *(uint4*)&pre16[g] = *(const uint4*)&Uh[idx];
    }
}

// ---------------------------------------------------------------------------
// CSR build, bucketed (dst>>8): count -> scan -> scatter -> fill.
// ---------------------------------------------------------------------------
__global__ __launch_bounds__(256) void k_count(const int* __restrict__ dst,
                                               int* __restrict__ cnt)
{
    __shared__ int lc[NB];
    const int tid = threadIdx.x;
    for (int i = tid; i < NB; i += 256) lc[i] = 0;
    __syncthreads();
    const int e0 = blockIdx.x * CHK, e1 = min(e0 + CHK, E_);
    for (int e = e0 + tid; e < e1; e += 256)
        atomicAdd(&lc[dst[e] >> 8], 1);
    __syncthreads();
    for (int i = tid; i < NB; i += 256) cnt[i * GB + blockIdx.x] = lc[i];
}

__global__ void k_bsum(const int* __restrict__ v, int* __restrict__ part, int L)
{
    __shared__ int s[256];
    int i = blockIdx.x * 256 + threadIdx.x;
    int t = threadIdx.x;
    s[t] = (i < L) ? v[i] : 0;
    __syncthreads();
    for (int st = 128; st > 0; st >>= 1) {
        if (t < st) s[t] += s[t + st];
        __syncthreads();
    }
    if (t == 0) part[blockIdx.x] = s[0];
}

__global__ void k_pscan(const int* __restrict__ part, int* __restrict__ poff, int nb)
{
    __shared__ int s[512];
    int t = threadIdx.x;
    int d = (t < nb) ? part[t] : 0;
    s[t] = d;
    __syncthreads();
    for (int st = 1; st < 512; st <<= 1) {
        int v = (t >= st) ? s[t - st] : 0;
        __syncthreads();
        s[t] += v;
        __syncthreads();
    }
    if (t < nb) poff[t] = s[t] - d;
}

__global__ void k_scan_excl(const int* __restrict__ v, const int* __restrict__ poff,
                            int* __restrict__ outp, int L)
{
    __shared__ int s[256];
    int i = blockIdx.x * 256 + threadIdx.x;
    int t = threadIdx.x;
    int d = (i < L) ? v[i] : 0;
    s[t] = d;
    __syncthreads();
    for (int st = 1; st < 256; st <<= 1) {
        int vv = (t >= st) ? s[t - st] : 0;
        __syncthreads();
        s[t] += vv;
        __syncthreads();
    }
    if (i < L) outp[i] = s[t] - d + poff[blockIdx.x];
}

// Phase C: scatter edges into bucket-ordered ebuf (uint2{src,dst}).
__global__ __launch_bounds__(256) void k_scatter(const int* __restrict__ src,
                                                 const int* __restrict__ dst,
                                                 const int* __restrict__ escan,
                                                 uint2* __restrict__ ebuf)
{
    __shared__ int lcur[NB];
    const int tid = threadIdx.x;
    for (int i = tid; i < NB; i += 256) lcur[i] = escan[i * GB + blockIdx.x];
    __syncthreads();
    const int e0 = blockIdx.x * CHK, e1 = min(e0 + CHK, E_);
    for (int e = e0 + tid; e < e1; e += 256) {
        int s = src[e], d = dst[e];
        int pos = atomicAdd(&lcur[d >> 8], 1);
        ebuf[pos] = uint2{(u32)s, (u32)d};
    }
}

// Phase D: per-bucket node offsets (LDS hist+scan) + csr fill. One block/bucket.
__global__ __launch_bounds__(256) void k_fill2(const uint2* __restrict__ ebuf,
                                               const int* __restrict__ escan,
                                               int* __restrict__ offs,
                                               int* __restrict__ endp,
                                               int* __restrict__ csr)
{
    __shared__ int hist[256], sc[256], cur[256];
    const int tid = threadIdx.x, b = blockIdx.x;
    const int s = escan[b * GB];
    const int e = (b == NB - 1) ? E_ : escan[(b + 1) * GB];
    hist[tid] = 0;
    __syncthreads();
    for (int i = s + tid; i < e; i += 256)
        atomicAdd(&hist[ebuf[i].y & 255], 1);
    __syncthreads();
    int d = hist[tid];
    sc[tid] = d;
    __syncthreads();
    for (int st = 1; st < 256; st <<= 1) {
        int v = (tid >= st) ? sc[tid - st] : 0;
        __syncthreads();
        sc[tid] += v;
        __syncthreads();
    }
    int ex = s + sc[tid] - d;
    int node = (b << 8) + tid;
    if (node < N_) { offs[node] = ex; endp[node] = ex + d; }
    cur[tid] = ex;
    __syncthreads();
    for (int i = s + tid; i < e; i += 256) {
        uint2 u = ebuf[i];
        int pos = atomicAdd(&cur[u.y & 255], 1);
        csr[pos] = u.x;
    }
}

// ---------------------------------------------------------------------------
// K2b: gather. One wave/node; lane covers 8 B (4 bf16 cols) via dwordx2;
// lane-halves process even/odd edges (2 edges per load inst), combine with
// shfl_xor(32). Unroll: 8 edges in flight.
// ---------------------------------------------------------------------------
__global__ __launch_bounds__(256) void k_agg(
    const u16* __restrict__ msg16, const int* __restrict__ csr,
    const int* __restrict__ offs, const int* __restrict__ endp,
    u32* __restrict__ agg16)
{
    const int w = threadIdx.x >> 6, l = threadIdx.x & 63;
    const int node = blockIdx.x * 4 + w;
    if (node >= N_) return;
    const int c = l & 31, h = l >> 5;
    const int s = offs[node], e = endp[node];
    float a0 = 0.f, a1 = 0.f, a2 = 0.f, a3 = 0.f;
    int i = s;
    for (; i + 8 <= e; i += 8) {
        uint2 d[4];
#pragma unroll
        for (int q = 0; q < 4; ++q) {
            int src = csr[i + 2 * q + h];
            d[q] = *(const uint2*)&((const u32*)(msg16 + (size_t)src * HD))[2 * c];
        }
#pragma unroll
        for (int q = 0; q < 4; ++q) {
            a0 += __uint_as_float(d[q].x << 16);
            a1 += __uint_as_float(d[q].x & 0xffff0000u);
            a2 += __uint_as_float(d[q].y << 16);
            a3 += __uint_as_float(d[q].y & 0xffff0000u);
        }
    }
    for (; i + 2 <= e; i += 2) {
        int src = csr[i + h];
        uint2 d = *(const uint2*)&((const u32*)(msg16 + (size_t)src * HD))[2 * c];
        a0 += __uint_as_float(d.x << 16);
        a1 += __uint_as_float(d.x & 0xffff0000u);
        a2 += __uint_as_float(d.y << 16);
        a3 += __uint_as_float(d.y & 0xffff0000u);
    }
    if (i < e && h == 0) {
        int src = csr[i];
        uint2 d = *(const uint2*)&((const u32*)(msg16 + (size_t)src * HD))[2 * c];
        a0 += __uint_as_float(d.x << 16);
        a1 += __uint_as_float(d.x & 0xffff0000u);
        a2 += __uint_as_float(d.y << 16);
        a3 += __uint_as_float(d.y & 0xffff0000u);
    }
    a0 += __shfl_xor(a0, 32);
    a1 += __shfl_xor(a1, 32);
    a2 += __shfl_xor(a2, 32);
    a3 += __shfl_xor(a3, 32);
    if (h == 0) {
        uint2 o;
        o.x = ((u32)f2bf(a1) << 16) | (u32)f2bf(a0);
        o.y = ((u32)f2bf(a3) << 16) | (u32)f2bf(a2);
        *(uint2*)&agg16[(size_t)node * 64 + 2 * c] = o;
    }
}

// ---------------------------------------------------------------------------
// K3: pre16 + agg16 -> P1 -> P2 -> P3 -> out.
// 32 nodes / 512-thread block (8 waves, one n-tile each). LDS 16 KB.
// ---------------------------------------------------------------------------
__global__ __launch_bounds__(512) void k_post(
    const u16* __restrict__ pre16, const u32* __restrict__ agg16,
    const float* __restrict__ pb1, const float* __restrict__ pb2,
    const float* __restrict__ P3, const float* __restrict__ pb3,
    const u16* __restrict__ wpk, float* __restrict__ out)
{
    __shared__ __align__(16) u16 Uh[4096], Vh[4096];
    const int tid = threadIdx.x;
    const int l = tid & 63, w = tid >> 6;
    const int base = blockIdx.x * 32;

    // load pre -> Uh, agg -> Vh (both single-plane bf16)
    {
        int e = tid * 8;
        int r = e >> 7, c0 = e & 127;
        int idx = r * HD + (c0 ^ ((r & 7) << 3));
        size_t g = (size_t)(base + r) * HD + c0;
        *(uint4*)&Uh[idx] = *(const uint4*)&pre16[g];
        *(uint4*)&Vh[idx] = *(const uint4*)&agg16[g >> 1];
    }
    __syncthreads();

    f32x4 acc[2];
    // P1 (K=256): kt 0-3 from Uh (pre), kt 4-7 from Vh (agg)
    {
        const float bv = pb1[w * 16 + (l & 15)];
        acc[0][0] = bv; acc[0][1] = bv; acc[0][2] = bv; acc[0][3] = bv;
        acc[1] = acc[0];
#pragma unroll
        for (int kt = 0; kt < 8; ++kt) {
            const u16* sh = (kt < 4) ? Uh : Vh;
            uint4 bh = *(const uint4*)&wpk[OFF_P1 + ((w * 8 + kt) * 64 + l) * 8];
            uint4 bl = *(const uint4*)&wpk[PK_TOT + OFF_P1 + ((w * 8 + kt) * 64 + l) * 8];
#pragma unroll
            for (int mt = 0; mt < 2; ++mt) {
                uint4 ah = ldsA(sh, mt * 16 + (l & 15), kt & 3, l);
                acc[mt] = mfma16(ah, bl, acc[mt]);
                acc[mt] = mfma16(ah, bh, acc[mt]);
            }
        }
    }
    __syncthreads();   // all P1 reads of Uh done before overwrite
    writeActH(Uh, acc[0], 0, w, l);
    writeActH(Uh, acc[1], 1, w, l);
    __syncthreads();

    // P2: U -> V (bf16, ReLU'd)
    mfmaLayerW<2, 4>(Uh, wpk + OFF_P2, wpk + PK_TOT + OFF_P2, pb2, w, l, acc);
    writeActH(Vh, acc[0], 0, w, l);
    writeActH(Vh, acc[1], 1, w, l);
    __syncthreads();

    // P3: 128 -> 16 + outer ReLU (VALU fp32; 512 thr = 32 nodes x 16 outs)
    {
        const int o = tid & 15;
        const int n = tid >> 4;
        const int sn = (n & 7) << 3;
        float a = pb3[o];
        for (int k0 = 0; k0 < HD; k0 += 8) {
            uint4 ph = *(const uint4*)&Vh[n * HD + (k0 ^ sn)];
            const u32 pw[4] = {ph.x, ph.y, ph.z, ph.w};
#pragma unroll
            for (int j = 0; j < 8; ++j) {
                u32 hv = (j & 1) ? (pw[j >> 1] & 0xffff0000u) : (pw[j >> 1] << 16);
                a += __uint_as_float(hv) * P3[(k0 + j) * 16 + o];
            }
        }
        out[(size_t)(base + n) * 16 + o] = fmaxf(a, 0.f);
    }
}

// ---------------------------------------------------------------------------
extern "C" void kernel_launch(void* const* d_in, const int* in_sizes, int n_in,
                              void* d_out, int out_size, void* d_ws, size_t ws_size,
                              hipStream_t stream)
{
    const float* x  = (const float*)d_in[0];
    const int*   ei = (const int*)d_in[1];
    const float* W1 = (const float*)d_in[2];  const float* b1  = (const float*)d_in[3];
    const float* W2 = (const float*)d_in[4];  const float* b2  = (const float*)d_in[5];
    const float* W3 = (const float*)d_in[6];  const float* b3  = (const float*)d_in[7];
    const float* Wl = (const float*)d_in[8];  const float* bl  = (const float*)d_in[9];
    const float* P1 = (const float*)d_in[10]; const float* pb1 = (const float*)d_in[11];
    const float* P2 = (const float*)d_in[12]; const float* pb2 = (const float*)d_in[13];
    const float* P3 = (const float*)d_in[14]; const float* pb3 = (const float*)d_in[15];
    float* out = (float*)d_out;

    // Workspace ~85.8 MB total
    char* ws = (char*)d_ws;
    u16* msg16  = (u16*)ws;   ws += (size_t)N_ * HD * 2;
    u32* agg16  = (u32*)ws;   ws += (size_t)N_ * 64 * 4;
    uint2* ebuf = (uint2*)agg16;                     // alias: dead before k_agg writes
    int* csr    = (int*)ws;   ws += (size_t)E_ * 4;
    int* offs   = (int*)ws;   ws += (size_t)N_ * 4;
    int* endp   = (int*)ws;   ws += (size_t)N_ * 4;
    int* cnt    = (int*)ws;   ws += (size_t)NBGB * 4;
    int* escan  = (int*)ws;   ws += (size_t)NBGB * 4;
    int* partC  = (int*)ws;   ws += 512 * 4;
    int* poffC  = (int*)ws;   ws += 512 * 4;
    u16* wpk    = (u16*)ws;   ws += (size_t)2 * PK_TOT * 2;
    u16* pre16  = (u16*)ws;   ws += (size_t)N_ * HD * 2;

    const int* srcv = ei;
    const int* dstv = ei + E_;
    const int nbC = NBGB / 256;   // 391 (exact)

    k_pack<<<(PK_TOT + 255) / 256, 256, 0, stream>>>(W2, W3, Wl, P2, P1, wpk);
    k_msg<<<N_ / 32, 512, 0, stream>>>(x, W1, b1, b2, b3, bl, wpk, msg16, pre16);
    k_count<<<GB, 256, 0, stream>>>(dstv, cnt);
    k_bsum<<<nbC, 256, 0, stream>>>(cnt, partC, NBGB);
    k_pscan<<<1, 512, 0, stream>>>(partC, poffC, nbC);
    k_scan_excl<<<nbC, 256, 0, stream>>>(cnt, poffC, escan, NBGB);
    k_scatter<<<GB, 256, 0, stream>>>(srcv, dstv, escan, ebuf);
    k_fill2<<<NB, 256, 0, stream>>>(ebuf, escan, offs, endp, csr);
    k_agg<<<(N_ + 3) / 4, 256, 0, stream>>>(msg16, csr, offs, endp, agg16);
    k_post<<<N_ / 32, 512, 0, stream>>>(pre16, agg16, pb1, pb2, P3, pb3, wpk, out);
}

// Round 12
// 190.659 us; speedup vs baseline: 1.4675x; 1.0815x over previous
//
#include <hip/hip_runtime.h>

#define N_ 100000
#define E_ 1600000
#define HD 128
#define NB 391      // dst buckets of 256 nodes (391*256 = 100096 >= N_)
#define GB 256      // binning blocks
#define CHK 6250    // edges per binning block (256*6250 = 1.6M exact)
#define NBGB (NB * GB)

typedef unsigned short u16;
typedef unsigned int u32;
typedef __bf16 bf16x8 __attribute__((ext_vector_type(8)));
typedef float f32x4 __attribute__((ext_vector_type(4)));

// packed-weight offsets (u16 elements) — single bf16 plane now
#define OFF_W2 0
#define OFF_W3 16384
#define OFF_WL 32768
#define OFF_P2 49152
#define OFF_P1 65536
#define PK_TOT 98304

__device__ __forceinline__ u16 f2bf(float f) {
    u32 u = __float_as_uint(f);
    return (u16)((u + 0x7FFFu + ((u >> 16) & 1u)) >> 16);
}
__device__ __forceinline__ f32x4 mfma16(uint4 a, uint4 b, f32x4 c) {
    return __builtin_amdgcn_mfma_f32_16x16x32_bf16(
        __builtin_bit_cast(bf16x8, a), __builtin_bit_cast(bf16x8, b), c, 0, 0, 0);
}

// Activation LDS layout (u16, [rows][128]): idx = row*128 + (col ^ ((row&7)<<3))
__device__ __forceinline__ uint4 ldsA(const u16* A, int row, int kt, int l) {
    int idx = row * 128 + (((kt * 32 + ((l >> 4) << 3))) ^ ((row & 7) << 3));
    return *(const uint4*)&A[idx];
}

// write C fragment (col=16*nt+(l&15), row=16*mt+4*(l>>4)+r) as ReLU'd bf16
__device__ __forceinline__ void writeActH(u16* Ah, f32x4 acc, int mt, int nt, int l) {
    const int col = nt * 16 + (l & 15);
#pragma unroll
    for (int r = 0; r < 4; ++r) {
        const int row = mt * 16 + ((l >> 4) << 2) + r;
        Ah[row * 128 + (col ^ ((row & 7) << 3))] = f2bf(fmaxf(acc[r], 0.f));
    }
}

// preload KT weight fragments (one n-tile) into registers
template<int KT>
__device__ __forceinline__ void loadW(const u16* __restrict__ wp, int nt, int l,
                                      uint4 wf[KT]) {
#pragma unroll
    for (int kt = 0; kt < KT; ++kt)
        wf[kt] = *(const uint4*)&wp[((nt * KT + kt) * 64 + l) * 8];
}

// MFMA layer with preloaded single-plane weights. MT=2 / 32-node blocks is the
// proven sweet spot (round 10: MT=4 -> 80-VGPR tier -> serialized, 2.5x slower).
template<int MT, int KT>
__device__ __forceinline__ void mfmaLayerP(const u16* Ah, const uint4 wf[KT],
                                           const float* __restrict__ bias,
                                           int nt, int l, f32x4 acc[MT])
{
    const float bv = bias[nt * 16 + (l & 15)];
#pragma unroll
    for (int mt = 0; mt < MT; ++mt) {
        acc[mt][0] = bv; acc[mt][1] = bv; acc[mt][2] = bv; acc[mt][3] = bv;
    }
#pragma unroll
    for (int kt = 0; kt < KT; ++kt)
#pragma unroll
        for (int mt = 0; mt < MT; ++mt) {
            uint4 ah = ldsA(Ah, mt * 16 + (l & 15), kt, l);
            acc[mt] = mfma16(ah, wf[kt], acc[mt]);
        }
}

// ---------------------------------------------------------------------------
// Weight pre-pack: fragment-ordered bf16 (single plane).
// ---------------------------------------------------------------------------
__global__ __launch_bounds__(256) void k_pack(
    const float* __restrict__ W2, const float* __restrict__ W3,
    const float* __restrict__ Wl, const float* __restrict__ P2,
    const float* __restrict__ P1, u16* __restrict__ wpk)
{
    int e = blockIdx.x * 256 + threadIdx.x;
    if (e >= PK_TOT) return;
    const float* src; int local, KT;
    if (e < OFF_P1) {
        int m = e >> 14;
        src = (m == 0) ? W2 : (m == 1) ? W3 : (m == 2) ? Wl : P2;
        local = e & 16383; KT = 4;
    } else {
        src = P1; local = e - OFF_P1; KT = 8;
    }
    int j = local & 7, lane = (local >> 3) & 63, t = local >> 9;
    int kt = t % KT, nt = t / KT;
    int k = kt * 32 + ((lane >> 4) << 3) + j;
    int n = nt * 16 + (lane & 15);
    wpk[e] = f2bf(src[k * HD + n]);
}

// ---------------------------------------------------------------------------
// layer1 (16 -> 128) VALU fp32 -> bf16 LDS. 512 thr: g=tid>>7, NPH=8.
// ---------------------------------------------------------------------------
template<int NPH>
__device__ __forceinline__ void layer1(const float xs[][16],
                                       const float* __restrict__ W1,
                                       const float* __restrict__ b1,
                                       u16* Uh, int f, int g)
{
    float w[16];
#pragma unroll
    for (int j = 0; j < 16; ++j) w[j] = W1[j * HD + f];
    const float bb = b1[f];
#pragma unroll
    for (int nn = 0; nn < NPH; ++nn) {
        const int row = g * NPH + nn;
        const float4* h4 = (const float4*)xs[row];
        float4 h0 = h4[0], h1 = h4[1], h2 = h4[2], h3 = h4[3];
        float a = bb
            + h0.x * w[0] + h0.y * w[1] + h0.z * w[2] + h0.w * w[3]
            + h1.x * w[4] + h1.y * w[5] + h1.z * w[6] + h1.w * w[7]
            + h2.x * w[8] + h2.y * w[9] + h2.z * w[10] + h2.w * w[11]
            + h3.x * w[12] + h3.y * w[13] + h3.z * w[14] + h3.w * w[15];
        Uh[row * 128 + (f ^ ((row & 7) << 3))] = f2bf(fmaxf(a, 0.f));
    }
}

// ---------------------------------------------------------------------------
// K1: mlp_pre + lin -> msg16 (bf16) + pre16 (bf16).
// 32 nodes / 512-thread block (8 waves, one n-tile each). LDS 18 KB.
// Weight fragments preloaded one layer ahead to hide L2 latency.
// ---------------------------------------------------------------------------
__global__ __launch_bounds__(512) void k_msg(
    const float* __restrict__ x,
    const float* __restrict__ W1, const float* __restrict__ b1,
    const float* __restrict__ b2, const float* __restrict__ b3,
    const float* __restrict__ blin,
    const u16* __restrict__ wpk, u16* __restrict__ msg16,
    u16* __restrict__ pre16)
{
    __shared__ float xs[32][16];
    __shared__ __align__(16) u16 Uh[4096], Vh[4096];
    const int tid = threadIdx.x;
    const int l = tid & 63, w = tid >> 6;   // w in [0,8)
    const int base = blockIdx.x * 32;

    uint4 wf2[4];
    loadW<4>(wpk + OFF_W2, w, l, wf2);      // W2 frags land during xs/layer1

    xs[tid >> 4][tid & 15] = x[(base + (tid >> 4)) * 16 + (tid & 15)];
    __syncthreads();

    layer1<8>(xs, W1, b1, Uh, tid & 127, tid >> 7);
    __syncthreads();

    f32x4 acc[2];
    // W2: U -> V
    mfmaLayerP<2, 4>(Uh, wf2, b2, w, l, acc);
    uint4 wf3[4];
    loadW<4>(wpk + OFF_W3, w, l, wf3);      // lands during writeAct+barrier
    writeActH(Vh, acc[0], 0, w, l);
    writeActH(Vh, acc[1], 1, w, l);
    __syncthreads();

    // W3: V -> U (U = pre)
    mfmaLayerP<2, 4>(Vh, wf3, b3, w, l, acc);
    uint4 wfl[4];
    loadW<4>(wpk + OFF_WL, w, l, wfl);
    writeActH(Uh, acc[0], 0, w, l);
    writeActH(Uh, acc[1], 1, w, l);
    __syncthreads();

    // lin: U -> V (bf16 msg)
    mfmaLayerP<2, 4>(Uh, wfl, blin, w, l, acc);
    writeActH(Vh, acc[0], 0, w, l);
    writeActH(Vh, acc[1], 1, w, l);
    __syncthreads();

    // coalesced stores: msg = Vh, pre = Uh
    {
        int e = tid * 8;
        int r = e >> 7, c0 = e & 127;
        int idx = r * HD + (c0 ^ ((r & 7) << 3));
        size_t g = (size_t)(base + r) * HD + c0;
        *(uint4*)&msg16[g] = *(const uint4*)&Vh[idx];
        *(uint4*)&pre16[g] = *(const uint4*)&Uh[idx];
    }
}

// ---------------------------------------------------------------------------
// CSR build, bucketed (dst>>8): count -> scan -> scatter -> fill.
// ---------------------------------------------------------------------------
__global__ __launch_bounds__(256) void k_count(const int* __restrict__ dst,
                                               int* __restrict__ cnt)
{
    __shared__ int lc[NB];
    const int tid = threadIdx.x;
    for (int i = tid; i < NB; i += 256) lc[i] = 0;
    __syncthreads();
    const int e0 = blockIdx.x * CHK, e1 = min(e0 + CHK, E_);
    for (int e = e0 + tid; e < e1; e += 256)
        atomicAdd(&lc[dst[e] >> 8], 1);
    __syncthreads();
    for (int i = tid; i < NB; i += 256) cnt[i * GB + blockIdx.x] = lc[i];
}

__global__ void k_bsum(const int* __restrict__ v, int* __restrict__ part, int L)
{
    __shared__ int s[256];
    int i = blockIdx.x * 256 + threadIdx.x;
    int t = threadIdx.x;
    s[t] = (i < L) ? v[i] : 0;
    __syncthreads();
    for (int st = 128; st > 0; st >>= 1) {
        if (t < st) s[t] += s[t + st];
        __syncthreads();
    }
    if (t == 0) part[blockIdx.x] = s[0];
}

__global__ void k_pscan(const int* __restrict__ part, int* __restrict__ poff, int nb)
{
    __shared__ int s[512];
    int t = threadIdx.x;
    int d = (t < nb) ? part[t] : 0;
    s[t] = d;
    __syncthreads();
    for (int st = 1; st < 512; st <<= 1) {
        int v = (t >= st) ? s[t - st] : 0;
        __syncthreads();
        s[t] += v;
        __syncthreads();
    }
    if (t < nb) poff[t] = s[t] - d;
}

__global__ void k_scan_excl(const int* __restrict__ v, const int* __restrict__ poff,
                            int* __restrict__ outp, int L)
{
    __shared__ int s[256];
    int i = blockIdx.x * 256 + threadIdx.x;
    int t = threadIdx.x;
    int d = (i < L) ? v[i] : 0;
    s[t] = d;
    __syncthreads();
    for (int st = 1; st < 256; st <<= 1) {
        int vv = (t >= st) ? s[t - st] : 0;
        __syncthreads();
        s[t] += vv;
        __syncthreads();
    }
    if (i < L) outp[i] = s[t] - d + poff[blockIdx.x];
}

// Phase C: scatter edges into bucket-ordered ebuf (uint2{src,dst}).
__global__ __launch_bounds__(256) void k_scatter(const int* __restrict__ src,
                                                 const int* __restrict__ dst,
                                                 const int* __restrict__ escan,
                                                 uint2* __restrict__ ebuf)
{
    __shared__ int lcur[NB];
    const int tid = threadIdx.x;
    for (int i = tid; i < NB; i += 256) lcur[i] = escan[i * GB + blockIdx.x];
    __syncthreads();
    const int e0 = blockIdx.x * CHK, e1 = min(e0 + CHK, E_);
    for (int e = e0 + tid; e < e1; e += 256) {
        int s = src[e], d = dst[e];
        int pos = atomicAdd(&lcur[d >> 8], 1);
        ebuf[pos] = uint2{(u32)s, (u32)d};
    }
}

// Phase D: per-bucket node offsets (LDS hist+scan) + csr fill. One block/bucket.
__global__ __launch_bounds__(256) void k_fill2(const uint2* __restrict__ ebuf,
                                               const int* __restrict__ escan,
                                               int* __restrict__ offs,
                                               int* __restrict__ endp,
                                               int* __restrict__ csr)
{
    __shared__ int hist[256], sc[256], cur[256];
    const int tid = threadIdx.x, b = blockIdx.x;
    const int s = escan[b * GB];
    const int e = (b == NB - 1) ? E_ : escan[(b + 1) * GB];
    hist[tid] = 0;
    __syncthreads();
    for (int i = s + tid; i < e; i += 256)
        atomicAdd(&hist[ebuf[i].y & 255], 1);
    __syncthreads();
    int d = hist[tid];
    sc[tid] = d;
    __syncthreads();
    for (int st = 1; st < 256; st <<= 1) {
        int v = (tid >= st) ? sc[tid - st] : 0;
        __syncthreads();
        sc[tid] += v;
        __syncthreads();
    }
    int ex = s + sc[tid] - d;
    int node = (b << 8) + tid;
    if (node < N_) { offs[node] = ex; endp[node] = ex + d; }
    cur[tid] = ex;
    __syncthreads();
    for (int i = s + tid; i < e; i += 256) {
        uint2 u = ebuf[i];
        int pos = atomicAdd(&cur[u.y & 255], 1);
        csr[pos] = u.x;
    }
}

// ---------------------------------------------------------------------------
// K2b: gather. One wave/node; lane covers 8 B (4 bf16 cols) via dwordx2;
// lane-halves process even/odd edges, combine with shfl_xor(32).
// ---------------------------------------------------------------------------
__global__ __launch_bounds__(256) void k_agg(
    const u16* __restrict__ msg16, const int* __restrict__ csr,
    const int* __restrict__ offs, const int* __restrict__ endp,
    u32* __restrict__ agg16)
{
    const int w = threadIdx.x >> 6, l = threadIdx.x & 63;
    const int node = blockIdx.x * 4 + w;
    if (node >= N_) return;
    const int c = l & 31, h = l >> 5;
    const int s = offs[node], e = endp[node];
    float a0 = 0.f, a1 = 0.f, a2 = 0.f, a3 = 0.f;
    int i = s;
    for (; i + 8 <= e; i += 8) {
        uint2 d[4];
#pragma unroll
        for (int q = 0; q < 4; ++q) {
            int src = csr[i + 2 * q + h];
            d[q] = *(const uint2*)&((const u32*)(msg16 + (size_t)src * HD))[2 * c];
        }
#pragma unroll
        for (int q = 0; q < 4; ++q) {
            a0 += __uint_as_float(d[q].x << 16);
            a1 += __uint_as_float(d[q].x & 0xffff0000u);
            a2 += __uint_as_float(d[q].y << 16);
            a3 += __uint_as_float(d[q].y & 0xffff0000u);
        }
    }
    for (; i + 2 <= e; i += 2) {
        int src = csr[i + h];
        uint2 d = *(const uint2*)&((const u32*)(msg16 + (size_t)src * HD))[2 * c];
        a0 += __uint_as_float(d.x << 16);
        a1 += __uint_as_float(d.x & 0xffff0000u);
        a2 += __uint_as_float(d.y << 16);
        a3 += __uint_as_float(d.y & 0xffff0000u);
    }
    if (i < e && h == 0) {
        int src = csr[i];
        uint2 d = *(const uint2*)&((const u32*)(msg16 + (size_t)src * HD))[2 * c];
        a0 += __uint_as_float(d.x << 16);
        a1 += __uint_as_float(d.x & 0xffff0000u);
        a2 += __uint_as_float(d.y << 16);
        a3 += __uint_as_float(d.y & 0xffff0000u);
    }
    a0 += __shfl_xor(a0, 32);
    a1 += __shfl_xor(a1, 32);
    a2 += __shfl_xor(a2, 32);
    a3 += __shfl_xor(a3, 32);
    if (h == 0) {
        uint2 o;
        o.x = ((u32)f2bf(a1) << 16) | (u32)f2bf(a0);
        o.y = ((u32)f2bf(a3) << 16) | (u32)f2bf(a2);
        *(uint2*)&agg16[(size_t)node * 64 + 2 * c] = o;
    }
}

// ---------------------------------------------------------------------------
// K3: pre16 + agg16 -> P1 -> P2 -> P3 -> out.
// 32 nodes / 512-thread block. LDS 16 KB. All weight frags preloaded to regs.
// ---------------------------------------------------------------------------
__global__ __launch_bounds__(512) void k_post(
    const u16* __restrict__ pre16, const u32* __restrict__ agg16,
    const float* __restrict__ pb1, const float* __restrict__ pb2,
    const float* __restrict__ P3, const float* __restrict__ pb3,
    const u16* __restrict__ wpk, float* __restrict__ out)
{
    __shared__ __align__(16) u16 Uh[4096], Vh[4096];
    const int tid = threadIdx.x;
    const int l = tid & 63, w = tid >> 6;
    const int base = blockIdx.x * 32;

    uint4 p1f[8];
    loadW<8>(wpk + OFF_P1, w, l, p1f);      // issue first; lands during LDS fill

    // load pre -> Uh, agg -> Vh (both single-plane bf16)
    {
        int e = tid * 8;
        int r = e >> 7, c0 = e & 127;
        int idx = r * HD + (c0 ^ ((r & 7) << 3));
        size_t g = (size_t)(base + r) * HD + c0;
        *(uint4*)&Uh[idx] = *(const uint4*)&pre16[g];
        *(uint4*)&Vh[idx] = *(const uint4*)&agg16[g >> 1];
    }
    __syncthreads();

    f32x4 acc[2];
    // P1 (K=256): kt 0-3 from Uh (pre), kt 4-7 from Vh (agg)
    {
        const float bv = pb1[w * 16 + (l & 15)];
        acc[0][0] = bv; acc[0][1] = bv; acc[0][2] = bv; acc[0][3] = bv;
        acc[1] = acc[0];
#pragma unroll
        for (int kt = 0; kt < 8; ++kt) {
            const u16* sh = (kt < 4) ? Uh : Vh;
#pragma unroll
            for (int mt = 0; mt < 2; ++mt) {
                uint4 ah = ldsA(sh, mt * 16 + (l & 15), kt & 3, l);
                acc[mt] = mfma16(ah, p1f[kt], acc[mt]);
            }
        }
    }
    uint4 p2f[4];
    loadW<4>(wpk + OFF_P2, w, l, p2f);      // lands during barriers+writeAct
    __syncthreads();   // all P1 reads of Uh done before overwrite
    writeActH(Uh, acc[0], 0, w, l);
    writeActH(Uh, acc[1], 1, w, l);
    __syncthreads();

    // P2: U -> V (bf16, ReLU'd)
    mfmaLayerP<2, 4>(Uh, p2f, pb2, w, l, acc);
    writeActH(Vh, acc[0], 0, w, l);
    writeActH(Vh, acc[1], 1, w, l);
    __syncthreads();

    // P3: 128 -> 16 + outer ReLU (VALU fp32; 512 thr = 32 nodes x 16 outs)
    {
        const int o = tid & 15;
        const int n = tid >> 4;
        const int sn = (n & 7) << 3;
        float a = pb3[o];
        for (int k0 = 0; k0 < HD; k0 += 8) {
            uint4 ph = *(const uint4*)&Vh[n * HD + (k0 ^ sn)];
            const u32 pw[4] = {ph.x, ph.y, ph.z, ph.w};
#pragma unroll
            for (int j = 0; j < 8; ++j) {
                u32 hv = (j & 1) ? (pw[j >> 1] & 0xffff0000u) : (pw[j >> 1] << 16);
                a += __uint_as_float(hv) * P3[(k0 + j) * 16 + o];
            }
        }
        out[(size_t)(base + n) * 16 + o] = fmaxf(a, 0.f);
    }
}

// ---------------------------------------------------------------------------
extern "C" void kernel_launch(void* const* d_in, const int* in_sizes, int n_in,
                              void* d_out, int out_size, void* d_ws, size_t ws_size,
                              hipStream_t stream)
{
    const float* x  = (const float*)d_in[0];
    const int*   ei = (const int*)d_in[1];
    const float* W1 = (const float*)d_in[2];  const float* b1  = (const float*)d_in[3];
    const float* W2 = (const float*)d_in[4];  const float* b2  = (const float*)d_in[5];
    const float* W3 = (const float*)d_in[6];  const float* b3  = (const float*)d_in[7];
    const float* Wl = (const float*)d_in[8];  const float* bl  = (const float*)d_in[9];
    const float* P1 = (const float*)d_in[10]; const float* pb1 = (const float*)d_in[11];
    const float* P2 = (const float*)d_in[12]; const float* pb2 = (const float*)d_in[13];
    const float* P3 = (const float*)d_in[14]; const float* pb3 = (const float*)d_in[15];
    float* out = (float*)d_out;

    // Workspace ~85.6 MB total
    char* ws = (char*)d_ws;
    u16* msg16  = (u16*)ws;   ws += (size_t)N_ * HD * 2;
    u32* agg16  = (u32*)ws;   ws += (size_t)N_ * 64 * 4;
    uint2* ebuf = (uint2*)agg16;                     // alias: dead before k_agg writes
    int* csr    = (int*)ws;   ws += (size_t)E_ * 4;
    int* offs   = (int*)ws;   ws += (size_t)N_ * 4;
    int* endp   = (int*)ws;   ws += (size_t)N_ * 4;
    int* cnt    = (int*)ws;   ws += (size_t)NBGB * 4;
    int* escan  = (int*)ws;   ws += (size_t)NBGB * 4;
    int* partC  = (int*)ws;   ws += 512 * 4;
    int* poffC  = (int*)ws;   ws += 512 * 4;
    u16* wpk    = (u16*)ws;   ws += (size_t)PK_TOT * 2;
    u16* pre16  = (u16*)ws;   ws += (size_t)N_ * HD * 2;

    const int* srcv = ei;
    const int* dstv = ei + E_;
    const int nbC = NBGB / 256;   // 391 (exact)

    k_pack<<<(PK_TOT + 255) / 256, 256, 0, stream>>>(W2, W3, Wl, P2, P1, wpk);
    k_msg<<<N_ / 32, 512, 0, stream>>>(x, W1, b1, b2, b3, bl, wpk, msg16, pre16);
    k_count<<<GB, 256, 0, stream>>>(dstv, cnt);
    k_bsum<<<nbC, 256, 0, stream>>>(cnt, partC, NBGB);
    k_pscan<<<1, 512, 0, stream>>>(partC, poffC, nbC);
    k_scan_excl<<<nbC, 256, 0, stream>>>(cnt, poffC, escan, NBGB);
    k_scatter<<<GB, 256, 0, stream>>>(srcv, dstv, escan, ebuf);
    k_fill2<<<NB, 256, 0, stream>>>(ebuf, escan, offs, endp, csr);
    k_agg<<<(N_ + 3) / 4, 256, 0, stream>>>(msg16, csr, offs, endp, agg16);
    k_post<<<N_ / 32, 512, 0, stream>>>(pre16, agg16, pb1, pb2, P3, pb3, wpk, out);
}

// Round 13
// 186.101 us; speedup vs baseline: 1.5034x; 1.0245x over previous
//
#include <hip/hip_runtime.h>

#define N_ 100000
#define E_ 1600000
#define HD 128
#define NB 391      // dst buckets of 256 nodes (391*256 = 100096 >= N_)
#define GB 256      // binning blocks
#define CHK 6250    // edges per binning block (256*6250 = 1.6M exact)
#define NBGB (NB * GB)

typedef unsigned short u16;
typedef unsigned int u32;
typedef __bf16 bf16x8 __attribute__((ext_vector_type(8)));
typedef float f32x4 __attribute__((ext_vector_type(4)));

// packed-weight offsets (u16 elements) — single bf16 plane
#define OFF_W2 0
#define OFF_W3 16384
#define OFF_WL 32768
#define OFF_P2 49152
#define OFF_P1 65536
#define PK_TOT 98304

__device__ __forceinline__ u16 f2bf(float f) {
    u32 u = __float_as_uint(f);
    return (u16)((u + 0x7FFFu + ((u >> 16) & 1u)) >> 16);
}
__device__ __forceinline__ f32x4 mfma16(uint4 a, uint4 b, f32x4 c) {
    return __builtin_amdgcn_mfma_f32_16x16x32_bf16(
        __builtin_bit_cast(bf16x8, a), __builtin_bit_cast(bf16x8, b), c, 0, 0, 0);
}

// Activation LDS layout (u16, [rows][128]): idx = row*128 + (col ^ ((row&7)<<3))
__device__ __forceinline__ uint4 ldsA(const u16* A, int row, int kt, int l) {
    int idx = row * 128 + (((kt * 32 + ((l >> 4) << 3))) ^ ((row & 7) << 3));
    return *(const uint4*)&A[idx];
}

// write C fragment (col=16*nt+(l&15), row=16*mt+4*(l>>4)+r) as ReLU'd bf16
__device__ __forceinline__ void writeActH(u16* Ah, f32x4 acc, int mt, int nt, int l) {
    const int col = nt * 16 + (l & 15);
#pragma unroll
    for (int r = 0; r < 4; ++r) {
        const int row = mt * 16 + ((l >> 4) << 2) + r;
        Ah[row * 128 + (col ^ ((row & 7) << 3))] = f2bf(fmaxf(acc[r], 0.f));
    }
}

// preload KT weight fragments (one n-tile) into registers
template<int KT>
__device__ __forceinline__ void loadW(const u16* __restrict__ wp, int nt, int l,
                                      uint4 wf[KT]) {
#pragma unroll
    for (int kt = 0; kt < KT; ++kt)
        wf[kt] = *(const uint4*)&wp[((nt * KT + kt) * 64 + l) * 8];
}

// MFMA layer with preloaded single-plane weights. MT=2 / 32-node blocks is the
// proven sweet spot (round 10: MT=4 -> 80-VGPR tier -> serialized, 2.5x slower).
template<int MT, int KT>
__device__ __forceinline__ void mfmaLayerP(const u16* Ah, const uint4 wf[KT],
                                           const float* __restrict__ bias,
                                           int nt, int l, f32x4 acc[MT])
{
    const float bv = bias[nt * 16 + (l & 15)];
#pragma unroll
    for (int mt = 0; mt < MT; ++mt) {
        acc[mt][0] = bv; acc[mt][1] = bv; acc[mt][2] = bv; acc[mt][3] = bv;
    }
#pragma unroll
    for (int kt = 0; kt < KT; ++kt)
#pragma unroll
        for (int mt = 0; mt < MT; ++mt) {
            uint4 ah = ldsA(Ah, mt * 16 + (l & 15), kt, l);
            acc[mt] = mfma16(ah, wf[kt], acc[mt]);
        }
}

// ---------------------------------------------------------------------------
// Weight pre-pack: fragment-ordered bf16 (single plane).
// ---------------------------------------------------------------------------
__global__ __launch_bounds__(256) void k_pack(
    const float* __restrict__ W2, const float* __restrict__ W3,
    const float* __restrict__ Wl, const float* __restrict__ P2,
    const float* __restrict__ P1, u16* __restrict__ wpk)
{
    int e = blockIdx.x * 256 + threadIdx.x;
    if (e >= PK_TOT) return;
    const float* src; int local, KT;
    if (e < OFF_P1) {
        int m = e >> 14;
        src = (m == 0) ? W2 : (m == 1) ? W3 : (m == 2) ? Wl : P2;
        local = e & 16383; KT = 4;
    } else {
        src = P1; local = e - OFF_P1; KT = 8;
    }
    int j = local & 7, lane = (local >> 3) & 63, t = local >> 9;
    int kt = t % KT, nt = t / KT;
    int k = kt * 32 + ((lane >> 4) << 3) + j;
    int n = nt * 16 + (lane & 15);
    wpk[e] = f2bf(src[k * HD + n]);
}

// ---------------------------------------------------------------------------
// layer1 (16 -> 128) VALU fp32 -> bf16 LDS. 512 thr: g=tid>>7, NPH=8.
// ---------------------------------------------------------------------------
template<int NPH>
__device__ __forceinline__ void layer1(const float xs[][16],
                                       const float* __restrict__ W1,
                                       const float* __restrict__ b1,
                                       u16* Uh, int f, int g)
{
    float w[16];
#pragma unroll
    for (int j = 0; j < 16; ++j) w[j] = W1[j * HD + f];
    const float bb = b1[f];
#pragma unroll
    for (int nn = 0; nn < NPH; ++nn) {
        const int row = g * NPH + nn;
        const float4* h4 = (const float4*)xs[row];
        float4 h0 = h4[0], h1 = h4[1], h2 = h4[2], h3 = h4[3];
        float a = bb
            + h0.x * w[0] + h0.y * w[1] + h0.z * w[2] + h0.w * w[3]
            + h1.x * w[4] + h1.y * w[5] + h1.z * w[6] + h1.w * w[7]
            + h2.x * w[8] + h2.y * w[9] + h2.z * w[10] + h2.w * w[11]
            + h3.x * w[12] + h3.y * w[13] + h3.z * w[14] + h3.w * w[15];
        Uh[row * 128 + (f ^ ((row & 7) << 3))] = f2bf(fmaxf(a, 0.f));
    }
}

// ---------------------------------------------------------------------------
// K1: mlp_pre + lin -> msg16 (bf16) + pre16 (bf16).
// 32 nodes / 512-thread block (8 waves, one n-tile each). LDS 18 KB.
// Weight fragments preloaded one layer ahead to hide L2 latency.
// ---------------------------------------------------------------------------
__global__ __launch_bounds__(512) void k_msg(
    const float* __restrict__ x,
    const float* __restrict__ W1, const float* __restrict__ b1,
    const float* __restrict__ b2, const float* __restrict__ b3,
    const float* __restrict__ blin,
    const u16* __restrict__ wpk, u16* __restrict__ msg16,
    u16* __restrict__ pre16)
{
    __shared__ float xs[32][16];
    __shared__ __align__(16) u16 Uh[4096], Vh[4096];
    const int tid = threadIdx.x;
    const int l = tid & 63, w = tid >> 6;   // w in [0,8)
    const int base = blockIdx.x * 32;

    uint4 wf2[4];
    loadW<4>(wpk + OFF_W2, w, l, wf2);      // W2 frags land during xs/layer1

    xs[tid >> 4][tid & 15] = x[(base + (tid >> 4)) * 16 + (tid & 15)];
    __syncthreads();

    layer1<8>(xs, W1, b1, Uh, tid & 127, tid >> 7);
    __syncthreads();

    f32x4 acc[2];
    // W2: U -> V
    mfmaLayerP<2, 4>(Uh, wf2, b2, w, l, acc);
    uint4 wf3[4];
    loadW<4>(wpk + OFF_W3, w, l, wf3);      // lands during writeAct+barrier
    writeActH(Vh, acc[0], 0, w, l);
    writeActH(Vh, acc[1], 1, w, l);
    __syncthreads();

    // W3: V -> U (U = pre)
    mfmaLayerP<2, 4>(Vh, wf3, b3, w, l, acc);
    uint4 wfl[4];
    loadW<4>(wpk + OFF_WL, w, l, wfl);
    writeActH(Uh, acc[0], 0, w, l);
    writeActH(Uh, acc[1], 1, w, l);
    __syncthreads();

    // lin: U -> V (bf16 msg)
    mfmaLayerP<2, 4>(Uh, wfl, blin, w, l, acc);
    writeActH(Vh, acc[0], 0, w, l);
    writeActH(Vh, acc[1], 1, w, l);
    __syncthreads();

    // coalesced stores: msg = Vh, pre = Uh
    {
        int e = tid * 8;
        int r = e >> 7, c0 = e & 127;
        int idx = r * HD + (c0 ^ ((r & 7) << 3));
        size_t g = (size_t)(base + r) * HD + c0;
        *(uint4*)&msg16[g] = *(const uint4*)&Vh[idx];
        *(uint4*)&pre16[g] = *(const uint4*)&Uh[idx];
    }
}

// ---------------------------------------------------------------------------
// CSR build, bucketed (dst>>8): count -> scan -> scatter -> fill.
// ---------------------------------------------------------------------------
__global__ __launch_bounds__(256) void k_count(const int* __restrict__ dst,
                                               int* __restrict__ cnt)
{
    __shared__ int lc[NB];
    const int tid = threadIdx.x;
    for (int i = tid; i < NB; i += 256) lc[i] = 0;
    __syncthreads();
    const int e0 = blockIdx.x * CHK, e1 = min(e0 + CHK, E_);
    for (int e = e0 + tid; e < e1; e += 256)
        atomicAdd(&lc[dst[e] >> 8], 1);
    __syncthreads();
    for (int i = tid; i < NB; i += 256) cnt[i * GB + blockIdx.x] = lc[i];
}

__global__ void k_bsum(const int* __restrict__ v, int* __restrict__ part, int L)
{
    __shared__ int s[256];
    int i = blockIdx.x * 256 + threadIdx.x;
    int t = threadIdx.x;
    s[t] = (i < L) ? v[i] : 0;
    __syncthreads();
    for (int st = 128; st > 0; st >>= 1) {
        if (t < st) s[t] += s[t + st];
        __syncthreads();
    }
    if (t == 0) part[blockIdx.x] = s[0];
}

__global__ void k_pscan(const int* __restrict__ part, int* __restrict__ poff, int nb)
{
    __shared__ int s[512];
    int t = threadIdx.x;
    int d = (t < nb) ? part[t] : 0;
    s[t] = d;
    __syncthreads();
    for (int st = 1; st < 512; st <<= 1) {
        int v = (t >= st) ? s[t - st] : 0;
        __syncthreads();
        s[t] += v;
        __syncthreads();
    }
    if (t < nb) poff[t] = s[t] - d;
}

__global__ void k_scan_excl(const int* __restrict__ v, const int* __restrict__ poff,
                            int* __restrict__ outp, int L)
{
    __shared__ int s[256];
    int i = blockIdx.x * 256 + threadIdx.x;
    int t = threadIdx.x;
    int d = (i < L) ? v[i] : 0;
    s[t] = d;
    __syncthreads();
    for (int st = 1; st < 256; st <<= 1) {
        int vv = (t >= st) ? s[t - st] : 0;
        __syncthreads();
        s[t] += vv;
        __syncthreads();
    }
    if (i < L) outp[i] = s[t] - d + poff[blockIdx.x];
}

// Phase C: scatter edges into bucket-ordered ebuf.
// Packed u32: (dst&255)<<24 | src  (src < 2^17 fits easily in 24 bits).
__global__ __launch_bounds__(256) void k_scatter(const int* __restrict__ src,
                                                 const int* __restrict__ dst,
                                                 const int* __restrict__ escan,
                                                 u32* __restrict__ ebuf)
{
    __shared__ int lcur[NB];
    const int tid = threadIdx.x;
    for (int i = tid; i < NB; i += 256) lcur[i] = escan[i * GB + blockIdx.x];
    __syncthreads();
    const int e0 = blockIdx.x * CHK, e1 = min(e0 + CHK, E_);
    for (int e = e0 + tid; e < e1; e += 256) {
        int s = src[e], d = dst[e];
        int pos = atomicAdd(&lcur[d >> 8], 1);
        ebuf[pos] = ((u32)(d & 255) << 24) | (u32)s;
    }
}

// Phase D: per-bucket node offsets (LDS hist+scan) + csr fill. One block/bucket.
__global__ __launch_bounds__(256) void k_fill2(const u32* __restrict__ ebuf,
                                               const int* __restrict__ escan,
                                               int* __restrict__ offs,
                                               int* __restrict__ endp,
                                               int* __restrict__ csr)
{
    __shared__ int hist[256], sc[256], cur[256];
    const int tid = threadIdx.x, b = blockIdx.x;
    const int s = escan[b * GB];
    const int e = (b == NB - 1) ? E_ : escan[(b + 1) * GB];
    hist[tid] = 0;
    __syncthreads();
    for (int i = s + tid; i < e; i += 256)
        atomicAdd(&hist[ebuf[i] >> 24], 1);
    __syncthreads();
    int d = hist[tid];
    sc[tid] = d;
    __syncthreads();
    for (int st = 1; st < 256; st <<= 1) {
        int v = (tid >= st) ? sc[tid - st] : 0;
        __syncthreads();
        sc[tid] += v;
        __syncthreads();
    }
    int ex = s + sc[tid] - d;
    int node = (b << 8) + tid;
    if (node < N_) { offs[node] = ex; endp[node] = ex + d; }
    cur[tid] = ex;
    __syncthreads();
    for (int i = s + tid; i < e; i += 256) {
        u32 p = ebuf[i];
        int pos = atomicAdd(&cur[p >> 24], 1);
        csr[pos] = (int)(p & 0x00FFFFFFu);
    }
}

// ---------------------------------------------------------------------------
// K2b: gather. One wave/node; quarter-wave (16 lanes) x dwordx4 covers one
// full 256 B msg row -> 4 edges in flight per load instruction. Main loop
// keeps 16 edges (4 dwordx4) outstanding. Cross-group combine: shfl_xor 16/32.
// ---------------------------------------------------------------------------
__global__ __launch_bounds__(256) void k_agg(
    const u16* __restrict__ msg16, const int* __restrict__ csr,
    const int* __restrict__ offs, const int* __restrict__ endp,
    u32* __restrict__ agg16)
{
    const int w = threadIdx.x >> 6, l = threadIdx.x & 63;
    const int node = blockIdx.x * 4 + w;
    if (node >= N_) return;
    const int g = l >> 4;        // quarter-wave group: which edge slot
    const int c = l & 15;        // 16 B chunk within the row (cols 8c..8c+7)
    const int s = offs[node], e = endp[node];
    float a[8] = {0.f, 0.f, 0.f, 0.f, 0.f, 0.f, 0.f, 0.f};
    int i = s;
    // main: 16 edges per iter, 4 dwordx4 loads in flight
    for (; i + 16 <= e; i += 16) {
        uint4 d[4];
#pragma unroll
        for (int q = 0; q < 4; ++q) {
            int src = csr[i + 4 * q + g];
            d[q] = *(const uint4*)&msg16[(size_t)src * HD + c * 8];
        }
#pragma unroll
        for (int q = 0; q < 4; ++q) {
            const u32 dw[4] = {d[q].x, d[q].y, d[q].z, d[q].w};
#pragma unroll
            for (int j = 0; j < 4; ++j) {
                a[2 * j]     += __uint_as_float(dw[j] << 16);
                a[2 * j + 1] += __uint_as_float(dw[j] & 0xffff0000u);
            }
        }
    }
    // mid tail: 4 edges per iter
    for (; i + 4 <= e; i += 4) {
        int src = csr[i + g];
        uint4 d = *(const uint4*)&msg16[(size_t)src * HD + c * 8];
        const u32 dw[4] = {d.x, d.y, d.z, d.w};
#pragma unroll
        for (int j = 0; j < 4; ++j) {
            a[2 * j]     += __uint_as_float(dw[j] << 16);
            a[2 * j + 1] += __uint_as_float(dw[j] & 0xffff0000u);
        }
    }
    // ragged tail: groups g < (e - i) handle one edge each
    if (i < e && g < e - i) {
        int src = csr[i + g];
        uint4 d = *(const uint4*)&msg16[(size_t)src * HD + c * 8];
        const u32 dw[4] = {d.x, d.y, d.z, d.w};
#pragma unroll
        for (int j = 0; j < 4; ++j) {
            a[2 * j]     += __uint_as_float(dw[j] << 16);
            a[2 * j + 1] += __uint_as_float(dw[j] & 0xffff0000u);
        }
    }
    // combine the 4 quarter-wave groups
#pragma unroll
    for (int j = 0; j < 8; ++j) {
        a[j] += __shfl_xor(a[j], 16);
        a[j] += __shfl_xor(a[j], 32);
    }
    if (g == 0) {
        uint4 o;
        o.x = ((u32)f2bf(a[1]) << 16) | (u32)f2bf(a[0]);
        o.y = ((u32)f2bf(a[3]) << 16) | (u32)f2bf(a[2]);
        o.z = ((u32)f2bf(a[5]) << 16) | (u32)f2bf(a[4]);
        o.w = ((u32)f2bf(a[7]) << 16) | (u32)f2bf(a[6]);
        *(uint4*)&agg16[(size_t)node * 64 + c * 4] = o;
    }
}

// ---------------------------------------------------------------------------
// K3: pre16 + agg16 -> P1 -> P2 -> P3 -> out.
// 32 nodes / 512-thread block. LDS 16 KB. All weight frags preloaded to regs.
// ---------------------------------------------------------------------------
__global__ __launch_bounds__(512) void k_post(
    const u16* __restrict__ pre16, const u32* __restrict__ agg16,
    const float* __restrict__ pb1, const float* __restrict__ pb2,
    const float* __restrict__ P3, const float* __restrict__ pb3,
    const u16* __restrict__ wpk, float* __restrict__ out)
{
    __shared__ __align__(16) u16 Uh[4096], Vh[4096];
    const int tid = threadIdx.x;
    const int l = tid & 63, w = tid >> 6;
    const int base = blockIdx.x * 32;

    uint4 p1f[8];
    loadW<8>(wpk + OFF_P1, w, l, p1f);      // issue first; lands during LDS fill

    // load pre -> Uh, agg -> Vh (both single-plane bf16)
    {
        int e = tid * 8;
        int r = e >> 7, c0 = e & 127;
        int idx = r * HD + (c0 ^ ((r & 7) << 3));
        size_t g = (size_t)(base + r) * HD + c0;
        *(uint4*)&Uh[idx] = *(const uint4*)&pre16[g];
        *(uint4*)&Vh[idx] = *(const uint4*)&agg16[g >> 1];
    }
    __syncthreads();

    f32x4 acc[2];
    // P1 (K=256): kt 0-3 from Uh (pre), kt 4-7 from Vh (agg)
    {
        const float bv = pb1[w * 16 + (l & 15)];
        acc[0][0] = bv; acc[0][1] = bv; acc[0][2] = bv; acc[0][3] = bv;
        acc[1] = acc[0];
#pragma unroll
        for (int kt = 0; kt < 8; ++kt) {
            const u16* sh = (kt < 4) ? Uh : Vh;
#pragma unroll
            for (int mt = 0; mt < 2; ++mt) {
                uint4 ah = ldsA(sh, mt * 16 + (l & 15), kt & 3, l);
                acc[mt] = mfma16(ah, p1f[kt], acc[mt]);
            }
        }
    }
    uint4 p2f[4];
    loadW<4>(wpk + OFF_P2, w, l, p2f);      // lands during barriers+writeAct
    __syncthreads();   // all P1 reads of Uh done before overwrite
    writeActH(Uh, acc[0], 0, w, l);
    writeActH(Uh, acc[1], 1, w, l);
    __syncthreads();

    // P2: U -> V (bf16, ReLU'd)
    mfmaLayerP<2, 4>(Uh, p2f, pb2, w, l, acc);
    writeActH(Vh, acc[0], 0, w, l);
    writeActH(Vh, acc[1], 1, w, l);
    __syncthreads();

    // P3: 128 -> 16 + outer ReLU (VALU fp32; 512 thr = 32 nodes x 16 outs)
    {
        const int o = tid & 15;
        const int n = tid >> 4;
        const int sn = (n & 7) << 3;
        float a = pb3[o];
        for (int k0 = 0; k0 < HD; k0 += 8) {
            uint4 ph = *(const uint4*)&Vh[n * HD + (k0 ^ sn)];
            const u32 pw[4] = {ph.x, ph.y, ph.z, ph.w};
#pragma unroll
            for (int j = 0; j < 8; ++j) {
                u32 hv = (j & 1) ? (pw[j >> 1] & 0xffff0000u) : (pw[j >> 1] << 16);
                a += __uint_as_float(hv) * P3[(k0 + j) * 16 + o];
            }
        }
        out[(size_t)(base + n) * 16 + o] = fmaxf(a, 0.f);
    }
}

// ---------------------------------------------------------------------------
extern "C" void kernel_launch(void* const* d_in, const int* in_sizes, int n_in,
                              void* d_out, int out_size, void* d_ws, size_t ws_size,
                              hipStream_t stream)
{
    const float* x  = (const float*)d_in[0];
    const int*   ei = (const int*)d_in[1];
    const float* W1 = (const float*)d_in[2];  const float* b1  = (const float*)d_in[3];
    const float* W2 = (const float*)d_in[4];  const float* b2  = (const float*)d_in[5];
    const float* W3 = (const float*)d_in[6];  const float* b3  = (const float*)d_in[7];
    const float* Wl = (const float*)d_in[8];  const float* bl  = (const float*)d_in[9];
    const float* P1 = (const float*)d_in[10]; const float* pb1 = (const float*)d_in[11];
    const float* P2 = (const float*)d_in[12]; const float* pb2 = (const float*)d_in[13];
    const float* P3 = (const float*)d_in[14]; const float* pb3 = (const float*)d_in[15];
    float* out = (float*)d_out;

    // Workspace ~85.6 MB total
    char* ws = (char*)d_ws;
    u16* msg16  = (u16*)ws;   ws += (size_t)N_ * HD * 2;
    u32* agg16  = (u32*)ws;   ws += (size_t)N_ * 64 * 4;
    u32* ebuf   = (u32*)agg16;                   // alias: dead before k_agg writes
    int* csr    = (int*)ws;   ws += (size_t)E_ * 4;
    int* offs   = (int*)ws;   ws += (size_t)N_ * 4;
    int* endp   = (int*)ws;   ws += (size_t)N_ * 4;
    int* cnt    = (int*)ws;   ws += (size_t)NBGB * 4;
    int* escan  = (int*)ws;   ws += (size_t)NBGB * 4;
    int* partC  = (int*)ws;   ws += 512 * 4;
    int* poffC  = (int*)ws;   ws += 512 * 4;
    u16* wpk    = (u16*)ws;   ws += (size_t)PK_TOT * 2;
    u16* pre16  = (u16*)ws;   ws += (size_t)N_ * HD * 2;

    const int* srcv = ei;
    const int* dstv = ei + E_;
    const int nbC = NBGB / 256;   // 391 (exact)

    k_pack<<<(PK_TOT + 255) / 256, 256, 0, stream>>>(W2, W3, Wl, P2, P1, wpk);
    k_msg<<<N_ / 32, 512, 0, stream>>>(x, W1, b1, b2, b3, bl, wpk, msg16, pre16);
    k_count<<<GB, 256, 0, stream>>>(dstv, cnt);
    k_bsum<<<nbC, 256, 0, stream>>>(cnt, partC, NBGB);
    k_pscan<<<1, 512, 0, stream>>>(partC, poffC, nbC);
    k_scan_excl<<<nbC, 256, 0, stream>>>(cnt, poffC, escan, NBGB);
    k_scatter<<<GB, 256, 0, stream>>>(srcv, dstv, escan, ebuf);
    k_fill2<<<NB, 256, 0, stream>>>(ebuf, escan, offs, endp, csr);
    k_agg<<<(N_ + 3) / 4, 256, 0, stream>>>(msg16, csr, offs, endp, agg16);
    k_post<<<N_ / 32, 512, 0, stream>>>(pre16, agg16, pb1, pb2, P3, pb3, wpk, out);
}